// Round 19
// baseline (200.602 us; speedup 1.0000x reference)
//
#include <hip/hip_runtime.h>

typedef __attribute__((ext_vector_type(8))) __bf16 bf16x8;
typedef __attribute__((ext_vector_type(4))) __bf16 bf16x4;
typedef __attribute__((ext_vector_type(4))) float f32x4;
typedef __attribute__((ext_vector_type(16))) float f32x16;
typedef __attribute__((ext_vector_type(4))) unsigned int u32x4;

#define GLDS(g, l) __builtin_amdgcn_global_load_lds( \
    (const __attribute__((address_space(1))) void*)(g), \
    (__attribute__((address_space(3))) void*)(l), 16, 0, 0)

__device__ __forceinline__ unsigned cvtpk_bf16(float lo, float hi) {
    unsigned r;
    asm("v_cvt_pk_bf16_f32 %0, %1, %2" : "=v"(r) : "v"(lo), "v"(hi));
    return r;
}
__device__ __forceinline__ void pl32swap(unsigned& a, unsigned& b) {
    asm("v_permlane32_swap_b32 %0, %1" : "+v"(a), "+v"(b));
}

// ---- merged: z<3: fp32 q/k/v -> tiled bf16 A-layout [mt128][ks32][kc4][row128][8]
//              z==3: W [K][N] f32 -> tiled bf16 B-layout [nt128][ks32][kc4][col128][8]
__global__ __launch_bounds__(256) void cvtw(const float* __restrict__ q,
                                            const float* __restrict__ k,
                                            const float* __restrict__ v,
                                            __bf16* __restrict__ qo,
                                            __bf16* __restrict__ ko,
                                            __bf16* __restrict__ vo,
                                            const float* __restrict__ Wq,
                                            const float* __restrict__ Wk,
                                            const float* __restrict__ Wv,
                                            const float* __restrict__ Wo,
                                            __bf16* __restrict__ Oq,
                                            __bf16* __restrict__ Ok,
                                            __bf16* __restrict__ Ov,
                                            __bf16* __restrict__ Oo) {
    __shared__ __align__(16) __bf16 sb[128 * 64];
    __shared__ float lw[64][65];
    const int t = threadIdx.x;
    const int z = blockIdx.z;
    if (z < 3) {
        const float* src = z == 0 ? q : z == 1 ? k : v;
        __bf16* dst = z == 0 ? qo : z == 1 ? ko : vo;
        const int m0 = blockIdx.x * 128, kk0 = blockIdx.y * 64;
        #pragma unroll
        for (int i = 0; i < 4; i++) {
            int cid = i * 256 + t;
            int r = cid >> 3, cc = cid & 7;
            const float* p = src + (size_t)(m0 + r) * 1024 + kk0 + cc * 8;
            float4 a = *(const float4*)p;
            float4 b2 = *(const float4*)(p + 4);
            bf16x8 o;
            o[0] = (__bf16)a.x;  o[1] = (__bf16)a.y;  o[2] = (__bf16)a.z;  o[3] = (__bf16)a.w;
            o[4] = (__bf16)b2.x; o[5] = (__bf16)b2.y; o[6] = (__bf16)b2.z; o[7] = (__bf16)b2.w;
            *(bf16x8*)((char*)sb + r * 128 + ((cc ^ (r & 7)) << 4)) = o;
        }
        __syncthreads();
        #pragma unroll
        for (int i = 0; i < 4; i++) {
            int cid = i * 256 + t;
            int ch = cid >> 7, r = cid & 127;
            bf16x8 o = *(const bf16x8*)((const char*)sb + r * 128 + ((ch ^ (r & 7)) << 4));
            size_t off = (((size_t)blockIdx.x * 32 + blockIdx.y * 2 + (ch >> 2)) * 4 + (ch & 3)) * 1024
                       + (size_t)r * 8;
            *(bf16x8*)(dst + off) = o;
        }
    } else {
        const int wi = blockIdx.x >> 4;
        const float* W = wi == 0 ? Wq : wi == 1 ? Wk : wi == 2 ? Wv : Wo;
        __bf16* Wt2 = wi == 0 ? Oq : wi == 1 ? Ok : wi == 2 ? Ov : Oo;
        const int kt = blockIdx.y * 64, nt = (blockIdx.x & 15) * 64;
        const int r = t >> 4;
        const int c4 = (t & 15) * 4;
        #pragma unroll
        for (int rr = 0; rr < 64; rr += 16) {
            float4 vv = *(const float4*)&W[(size_t)(kt + r + rr) * 1024 + nt + c4];
            lw[r + rr][c4 + 0] = vv.x; lw[r + rr][c4 + 1] = vv.y;
            lw[r + rr][c4 + 2] = vv.z; lw[r + rr][c4 + 3] = vv.w;
        }
        __syncthreads();
        #pragma unroll
        for (int rr = 0; rr < 64; rr += 16) {
            int n = nt + r + rr;
            bf16x4 ov;
            #pragma unroll
            for (int i = 0; i < 4; i++) ov[i] = (__bf16)lw[c4 + i][r + rr];
            int kg = kt + c4;
            size_t off = (size_t)(n >> 7) * 131072 + (size_t)(kg >> 5) * 4096
                       + (size_t)((kg >> 3) & 3) * 1024 + (size_t)(n & 127) * 8 + (kg & 7);
            *(bf16x4*)&Wt2[off] = ov;
        }
    }
}

// ---- 8-phase GEMM: BM256 x BN128 x BK64, 8 waves (2Mx4N, wave 128x32),
//      3 LDS sides (48KB each), counted vmcnt(6) once per K-tile group.
//      Group g: compute tile g from side g%3; stage tile g+2 -> side (g+2)%3.
//      WAR-safe: side (g+2)%3 holds tile g-1, fully read before group g.
// QKV=1: mode=y+1 (1=Qp scaled row-major, 2=Kt tiled, 3=Vtt tiled); QKV=0: f32 row-major.
template <int QKV>
__global__ __launch_bounds__(512, 2)
void gemm8p(const __bf16* __restrict__ A0, const __bf16* __restrict__ A1,
            const __bf16* __restrict__ A2,
            const __bf16* __restrict__ B0, const __bf16* __restrict__ B1,
            const __bf16* __restrict__ B2,
            const float* __restrict__ bi0, const float* __restrict__ bi1,
            const float* __restrict__ bi2,
            void* __restrict__ C0, void* __restrict__ C1, void* __restrict__ C2) {
    __shared__ __align__(16) char S[3 * 49152];   // 3 sides x (A 32KB + B 16KB)
    const int y = blockIdx.y;
    const __bf16* At  = QKV ? (y == 0 ? A0 : y == 1 ? A1 : A2) : A0;
    const __bf16* Bt2 = QKV ? (y == 0 ? B0 : y == 1 ? B1 : B2) : B0;
    const float* bias = QKV ? (y == 0 ? bi0 : y == 1 ? bi1 : bi2) : bi0;
    void* Cout        = QKV ? (y == 0 ? C0 : y == 1 ? C1 : C2) : C0;
    const int mode    = QKV ? y + 1 : 0;

    const int t = threadIdx.x, l = t & 63;
    const int wv = t >> 6, wm = wv >> 2, wn = wv & 3;   // 2M x 4N waves
    const int bid = blockIdx.x;
    const int wgid = (bid & 7) * 32 + (bid >> 3);       // XCD-contiguous
    const int bm = wgid >> 3, bn = wgid & 7;            // 32 x 8 tiles
    const __bf16* Abase = At + (size_t)(2 * bm) * 131072;   // halves at +0, +131072
    const __bf16* Bbase = Bt2 + (size_t)bn * 131072;

    // per-thread invariant byte offsets within a side
    const int aoff = wm * 16384 + ((l >> 4) << 11) + ((l & 15) << 4);
    const int boff = 32768 + ((l >> 4) << 11) + ((wn * 32 + (l & 15)) << 4);

#define STGA8(T_, sd_) do { \
    const __bf16* s0_ = Abase + (size_t)(T_) * 8192; \
    char* d0_ = S + (sd_) * 49152; \
    GLDS(s0_ + t * 8,                 d0_ + t * 16); \
    GLDS(s0_ + 4096 + t * 8,          d0_ + 8192 + t * 16); \
    GLDS(s0_ + 131072 + t * 8,        d0_ + 16384 + t * 16); \
    GLDS(s0_ + 131072 + 4096 + t * 8, d0_ + 24576 + t * 16); \
} while (0)
#define STGB8(T_, sd_) do { \
    const __bf16* s1_ = Bbase + (size_t)(T_) * 8192; \
    char* d1_ = S + (sd_) * 49152 + 32768; \
    GLDS(s1_ + t * 8,        d1_ + t * 16); \
    GLDS(s1_ + 4096 + t * 8, d1_ + 8192 + t * 16); \
} while (0)

    f32x4 acc[8][2];
    #pragma unroll
    for (int i = 0; i < 8; i++) {
        acc[i][0] = (f32x4){0.f, 0.f, 0.f, 0.f};
        acc[i][1] = (f32x4){0.f, 0.f, 0.f, 0.f};
    }

    // prologue: tiles 0 -> side 0, 1 -> side 1 (12 loads); retire tile 0
    STGA8(0, 0); STGB8(0, 0);
    STGA8(1, 1); STGB8(1, 1);
    asm volatile("s_waitcnt vmcnt(6)" ::: "memory");
    __builtin_amdgcn_s_barrier();

    int cur = 0;
    #pragma unroll 1
    for (int g = 0; g < 16; ++g) {
        const int nxt = cur >= 1 ? cur - 1 : 2;         // (cur+2)%3 : holds tile g-1 (read-done)
        const char* sbp = (const char*)S + cur * 49152;
        // ===== phase 0: frags i 0..3 =====
        bf16x8 af0[4][2], bf0[2][2];
        #pragma unroll
        for (int ii = 0; ii < 4; ii++)
            #pragma unroll
            for (int s = 0; s < 2; s++)
                af0[ii][s] = *(const bf16x8*)(sbp + aoff + s * 8192 + ii * 256);
        #pragma unroll
        for (int j = 0; j < 2; j++)
            #pragma unroll
            for (int s = 0; s < 2; s++)
                bf0[j][s] = *(const bf16x8*)(sbp + boff + s * 8192 + j * 256);
        if (g <= 13) STGA8(g + 2, nxt);
        __builtin_amdgcn_s_barrier();
        asm volatile("s_waitcnt lgkmcnt(0)" ::: "memory");
        __builtin_amdgcn_sched_barrier(0);
        __builtin_amdgcn_s_setprio(1);
        #pragma unroll
        for (int s = 0; s < 2; s++)
            #pragma unroll
            for (int ii = 0; ii < 4; ii++)
                #pragma unroll
                for (int j = 0; j < 2; j++)
                    acc[ii][j] = __builtin_amdgcn_mfma_f32_16x16x32_bf16(
                        af0[ii][s], bf0[j][s], acc[ii][j], 0, 0, 0);
        __builtin_amdgcn_s_setprio(0);
        __builtin_amdgcn_s_barrier();
        // ===== phase 1: frags i 4..7 =====
        bf16x8 af1[4][2], bf1[2][2];
        #pragma unroll
        for (int ii = 0; ii < 4; ii++)
            #pragma unroll
            for (int s = 0; s < 2; s++)
                af1[ii][s] = *(const bf16x8*)(sbp + aoff + s * 8192 + (ii + 4) * 256);
        #pragma unroll
        for (int j = 0; j < 2; j++)
            #pragma unroll
            for (int s = 0; s < 2; s++)
                bf1[j][s] = *(const bf16x8*)(sbp + boff + s * 8192 + j * 256);
        if (g <= 13) STGB8(g + 2, nxt);
        // group-end checkpoint: retire tile g+1 (leave tile g+2's 6 loads in flight)
        if (g <= 13) asm volatile("s_waitcnt vmcnt(6)" ::: "memory");
        else         asm volatile("s_waitcnt vmcnt(0)" ::: "memory");
        __builtin_amdgcn_s_barrier();
        asm volatile("s_waitcnt lgkmcnt(0)" ::: "memory");
        __builtin_amdgcn_sched_barrier(0);
        __builtin_amdgcn_s_setprio(1);
        #pragma unroll
        for (int s = 0; s < 2; s++)
            #pragma unroll
            for (int ii = 0; ii < 4; ii++)
                #pragma unroll
                for (int j = 0; j < 2; j++)
                    acc[ii + 4][j] = __builtin_amdgcn_mfma_f32_16x16x32_bf16(
                        af1[ii][s], bf1[j][s], acc[ii + 4][j], 0, 0, 0);
        __builtin_amdgcn_s_setprio(0);
        __builtin_amdgcn_s_barrier();
        cur = cur == 2 ? 0 : cur + 1;
    }
#undef STGA8
#undef STGB8

    const int m0 = bm * 256 + wm * 128, n0 = bn * 128 + wn * 32;
    #pragma unroll
    for (int j = 0; j < 2; j++) {
        int col = n0 + j * 16 + (l & 15);
        float bv = bias[col];
        #pragma unroll
        for (int ii = 0; ii < 8; ii++) {
            #pragma unroll
            for (int r = 0; r < 4; r++) {
                int row = m0 + ii * 16 + (l >> 4) * 4 + r;
                float vvv = acc[ii][j][r] + bv;
                if (mode == 0) {
                    ((float*)Cout)[(size_t)row * 1024 + col] = vvv;
                } else if (mode == 1) {
                    ((__bf16*)Cout)[(size_t)row * 1024 + col] = (__bf16)(vvv * 0.18033688f);
                } else if (mode == 2) {
                    int b_ = row >> 11, s_ = row & 2047, h_ = col >> 6, hd_ = col & 63;
                    size_t off = ((size_t)(b_ * 16 + h_) * 32 + (s_ >> 6)) * 4096
                               + (size_t)(hd_ >> 3) * 512 + (s_ & 63) * 8 + (hd_ & 7);
                    ((__bf16*)Cout)[off] = (__bf16)vvv;
                } else {
                    int b_ = row >> 11, s_ = row & 2047, h_ = col >> 6, d_ = col & 63;
                    size_t off = ((size_t)(b_ * 16 + h_) * 32 + (s_ >> 6)) * 4096
                               + (size_t)((s_ & 63) >> 3) * 512 + (size_t)d_ * 8 + (s_ & 7);
                    ((__bf16*)Cout)[off] = (__bf16)vvv;
                }
            }
        }
    }
}

// ---- Flash attention: 8 waves x 32 q-rows, 256 rows/block, grid 512 (r14) ----
__global__ __launch_bounds__(512, 4)
void attn_fwd(const __bf16* __restrict__ Qp, const __bf16* __restrict__ Kt,
              const __bf16* __restrict__ Vtt, __bf16* __restrict__ AOt) {
    constexpr int S = 2048, D = 1024;
    __shared__ __align__(16) __bf16 sK[3 * 4096];
    __shared__ __align__(16) __bf16 sV[3 * 4096];
    __shared__ float sL[8][32];
    const int t = threadIdx.x, l = t & 63, w = t >> 6;   // w: 0..7
    const int c = l & 31, g = l >> 5;
    const int bid = blockIdx.x, slot = bid >> 3;
    const int bh = (slot >> 3) * 8 + (bid & 7);     // bh % 8 == XCD
    const int qb = slot & 7;                        // 8 q-blocks of 256 rows
    const int b = bh >> 4, h = bh & 15;
    const int q0 = qb * 256;
    const __bf16* Kb = Kt + (size_t)bh * 131072;
    const __bf16* Vb = Vtt + (size_t)bh * 131072;

    bf16x8 qf[4];
    {
        const __bf16* qp = Qp + (size_t)(b * S + q0 + w * 32 + c) * D + h * 64;
        #pragma unroll
        for (int ks = 0; ks < 4; ks++)
            qf[ks] = *(const bf16x8*)(qp + ks * 16 + g * 8);
    }
    asm volatile("s_waitcnt vmcnt(0)" ::: "memory");

#define AISSUE(ti_, buf_) do { \
    GLDS(Kb + (ti_) * 4096 + t * 8, (char*)sK + (buf_) * 8192 + t * 16); \
    GLDS(Vb + (ti_) * 4096 + t * 8, (char*)sV + (buf_) * 8192 + t * 16); \
} while (0)

    f32x16 acc[2];
    acc[0] = (f32x16){}; acc[1] = (f32x16){};
    float ls = 0.f;

    AISSUE(0, 0);
    AISSUE(1, 1);
    int cur = 0;
    #pragma unroll 1
    for (int tile = 0; tile < 32; ++tile) {
        if (tile < 31) asm volatile("s_waitcnt vmcnt(2)" ::: "memory");
        else           asm volatile("s_waitcnt vmcnt(0)" ::: "memory");
        __builtin_amdgcn_s_barrier();
        __builtin_amdgcn_sched_barrier(0);
        const __bf16* bK = sK + cur * 4096;
        const __bf16* bV = sV + cur * 4096;
        #pragma unroll
        for (int kt = 0; kt < 2; kt++) {
            bf16x8 kf[4];
            #pragma unroll
            for (int ks = 0; ks < 4; ks++)
                kf[ks] = *(const bf16x8*)(bK + ((2 * ks + g) * 64 + kt * 32 + c) * 8);
            bf16x8 vq0[2], vq1[2];
            #pragma unroll
            for (int ti = 0; ti < 2; ti++) {
                vq0[ti] = *(const bf16x8*)(bV + ((4 * kt + g) * 64 + ti * 32 + c) * 8);
                vq1[ti] = *(const bf16x8*)(bV + ((4 * kt + 2 + g) * 64 + ti * 32 + c) * 8);
            }
            f32x16 St = {};
            St = __builtin_amdgcn_mfma_f32_32x32x16_bf16(kf[0], qf[0], St, 0, 0, 0);
            St = __builtin_amdgcn_mfma_f32_32x32x16_bf16(kf[1], qf[1], St, 0, 0, 0);
            St = __builtin_amdgcn_mfma_f32_32x32x16_bf16(kf[2], qf[2], St, 0, 0, 0);
            St = __builtin_amdgcn_mfma_f32_32x32x16_bf16(kf[3], qf[3], St, 0, 0, 0);
            #pragma unroll
            for (int r2 = 0; r2 < 16; r2++) {
                float p = __builtin_amdgcn_exp2f(St[r2]);
                ls += p;
                St[r2] = p;
            }
            unsigned w0 = cvtpk_bf16(St[0], St[1]),   w1 = cvtpk_bf16(St[2], St[3]);
            unsigned w2 = cvtpk_bf16(St[4], St[5]),   w3 = cvtpk_bf16(St[6], St[7]);
            unsigned w4 = cvtpk_bf16(St[8], St[9]),   w5 = cvtpk_bf16(St[10], St[11]);
            unsigned w6 = cvtpk_bf16(St[12], St[13]), w7 = cvtpk_bf16(St[14], St[15]);
            pl32swap(w0, w2); pl32swap(w1, w3);
            pl32swap(w4, w6); pl32swap(w5, w7);
            bf16x8 pa0 = __builtin_bit_cast(bf16x8, (u32x4){w0, w1, w2, w3});
            bf16x8 pa1 = __builtin_bit_cast(bf16x8, (u32x4){w4, w5, w6, w7});
            acc[0] = __builtin_amdgcn_mfma_f32_32x32x16_bf16(pa0, vq0[0], acc[0], 0, 0, 0);
            acc[1] = __builtin_amdgcn_mfma_f32_32x32x16_bf16(pa0, vq0[1], acc[1], 0, 0, 0);
            acc[0] = __builtin_amdgcn_mfma_f32_32x32x16_bf16(pa1, vq1[0], acc[0], 0, 0, 0);
            acc[1] = __builtin_amdgcn_mfma_f32_32x32x16_bf16(pa1, vq1[1], acc[1], 0, 0, 0);
        }
        if (tile + 2 < 32) AISSUE(tile + 2, cur >= 1 ? cur - 1 : 2);
        cur = cur == 2 ? 0 : cur + 1;
    }
#undef AISSUE

    float tt = ls + __shfl_xor(ls, 32);
    if (l < 32) sL[w][l] = 1.0f / tt;
    __syncthreads();

    // write O in tiled-A layout [mt128][ks32][kc4][row128][8]; ks = h*2 + hi
    #pragma unroll
    for (int rq = 0; rq < 4; rq++)
        #pragma unroll
        for (int rr2 = 0; rr2 < 4; rr2++) {
            int reg = rq * 4 + rr2;
            int rloc = rr2 + 8 * rq + 4 * g;
            float rn = sL[w][rloc];
            int qloc = w * 32 + rloc;
            int mt = b * 16 + qb * 2 + (qloc >> 7);
            int mr = qloc & 127;
            size_t base = ((size_t)mt * 32 + h * 2) * 4096 + (size_t)(c >> 3) * 1024
                        + (size_t)mr * 8 + (c & 7);
            AOt[base] = (__bf16)(acc[0][reg] * rn);
            AOt[base + 4096] = (__bf16)(acc[1][reg] * rn);
        }
}

extern "C" void kernel_launch(void* const* d_in, const int* in_sizes, int n_in,
                              void* d_out, int out_size, void* d_ws, size_t ws_size,
                              hipStream_t stream) {
    const float* q  = (const float*)d_in[0];
    const float* k  = (const float*)d_in[1];
    const float* v  = (const float*)d_in[2];
    const float* Wq = (const float*)d_in[3];
    const float* bq = (const float*)d_in[4];
    const float* Wk = (const float*)d_in[5];
    const float* bk = (const float*)d_in[6];
    const float* Wv = (const float*)d_in[7];
    const float* bv = (const float*)d_in[8];
    const float* Wo = (const float*)d_in[9];
    const float* bo = (const float*)d_in[10];

    char* ws = (char*)d_ws;
    const size_t MiB = 1024 * 1024;
    __bf16* Atq = (__bf16*)(ws);             // tiled bf16 q (16MB); later reused as AOt
    __bf16* Atk = (__bf16*)(ws + 16 * MiB);
    __bf16* Atv = (__bf16*)(ws + 32 * MiB);
    __bf16* W2q = (__bf16*)(ws + 48 * MiB);
    __bf16* W2k = (__bf16*)(ws + 50 * MiB);
    __bf16* W2v = (__bf16*)(ws + 52 * MiB);
    __bf16* W2o = (__bf16*)(ws + 54 * MiB);
    __bf16* Qp  = (__bf16*)(ws + 56 * MiB);  // row-major bf16, pre-scaled
    __bf16* Kt  = (__bf16*)(ws + 72 * MiB);  // K tiled (attn layout)
    __bf16* Vtt = (__bf16*)(ws + 88 * MiB);  // V tiled (attn layout)
    __bf16* AOt = (__bf16*)(ws);             // attn out, A-tiled (aliases Atq, dead)

    // fused cvt (z<3) + weight transpose (z==3)
    cvtw<<<dim3(64, 16, 4), 256, 0, stream>>>(q, k, v, Atq, Atk, Atv,
                                              Wq, Wk, Wv, Wo, W2q, W2k, W2v, W2o);

    // Q/K/V projections (8-phase; grid.y selects operand set; modes 1,2,3)
    gemm8p<1><<<dim3(256, 3), 512, 0, stream>>>(Atq, Atk, Atv, W2q, W2k, W2v,
                                                bq, bk, bv, Qp, Kt, Vtt);

    attn_fwd<<<512, 512, 0, stream>>>(Qp, Kt, Vtt, AOt);

    // output projection (8-phase; mode 0: f32 row-major to d_out)
    gemm8p<0><<<dim3(256, 1), 512, 0, stream>>>(AOt, AOt, AOt, W2o, W2o, W2o,
                                                bo, bo, bo, d_out, d_out, d_out);
}